// Round 8
// baseline (176.241 us; speedup 1.0000x reference)
//
#include <hip/hip_runtime.h>

typedef _Float16 h4 __attribute__((ext_vector_type(4)));
typedef _Float16 h8 __attribute__((ext_vector_type(8)));
typedef float    f4 __attribute__((ext_vector_type(4)));

// SCALE * log2(e): softmax computed in exp2 domain (identical result).
// No max-subtraction: |s_scaled| < ~6 here -> exp2 in [2e-2, 45], fp16/fp32 safe.
#define QSCALE (0.25f * 1.44269504088896f)

__device__ __forceinline__ float ex2(float x){ return __builtin_amdgcn_exp2f(x); }

// ---------------- prep: fold BN into weights (weights only) ----------------
__global__ __launch_bounds__(256) void prep_k(
    const float* __restrict__ qkvw, const float* __restrict__ qg, const float* __restrict__ qb,
    const float* __restrict__ qm,   const float* __restrict__ qv,
    const float* __restrict__ pew,  const float* __restrict__ pg, const float* __restrict__ pb,
    const float* __restrict__ pm,   const float* __restrict__ pv,
    const float* __restrict__ prw,  const float* __restrict__ prg, const float* __restrict__ prb,
    const float* __restrict__ prm,  const float* __restrict__ prv,
    _Float16* __restrict__ Wqkv, float* __restrict__ bqkv,
    _Float16* __restrict__ Wproj, float* __restrict__ bproj,
    float* __restrict__ peW, float* __restrict__ peB)
{
  const int gid = blockIdx.x*256 + threadIdx.x;
  const int gsz = gridDim.x*256;
  for (int i = gid; i < 512*256; i += gsz){           // Wqkv[o][c] = w[c][o]*g*rs
    int o = i >> 8, c = i & 255;
    float s = qg[o] * rsqrtf(qv[o] + 1e-3f);
    Wqkv[i] = (_Float16)(qkvw[c*512 + o] * s);
  }
  for (int i = gid; i < 512; i += gsz){
    float s = qg[i] * rsqrtf(qv[i] + 1e-3f);
    bqkv[i] = qb[i] - qm[i]*s;
  }
  for (int i = gid; i < 256*256; i += gsz){
    int o = i >> 8, c = i & 255;
    float s = prg[o] * rsqrtf(prv[o] + 1e-3f);
    Wproj[i] = (_Float16)(prw[c*256 + o] * s);
  }
  for (int i = gid; i < 256; i += gsz){
    float s = prg[i] * rsqrtf(prv[i] + 1e-3f);
    bproj[i] = prb[i] - prm[i]*s;
  }
  for (int i = gid; i < 9*256; i += gsz){
    int c = i & 255;
    float s = pg[c] * rsqrtf(pv[c] + 1e-3f);
    peW[i] = pew[i] * s;
  }
  for (int i = gid; i < 256; i += gsz){
    float s = pg[i] * rsqrtf(pv[i] + 1e-3f);
    peB[i] = pb[i] - pm[i]*s;
  }
}

// ---------------- qkv GEMM: [8192 x 256 (f32)] x [512 x 256]^T -------------
// grid (128, 2): block = 64 m x 256 n (inner loop of 4 n-tiles). A staged
// ONCE (full K=256 panel, fp32->fp16 during staging) and reused across the
// n-loop -> X HBM traffic 16 MB instead of 64 MB. B tiles staged per n-tile
// with register prefetch. Waves 2x2 of 32m x 32n per n-tile.
__global__ __launch_bounds__(256) void qkv_gemm_k(
    const float* __restrict__ X, const _Float16* __restrict__ Wqkv,
    const float* __restrict__ bias,
    _Float16* __restrict__ Qh, _Float16* __restrict__ Kh, _Float16* __restrict__ Vh)
{
  __shared__ __align__(16) _Float16 As[64*264];   // row stride 264 halves (528 B)
  __shared__ __align__(16) _Float16 Bs[64*264];
  const int t = threadIdx.x, lane = t & 63, wv = t >> 6;
  const int l15 = lane & 15, q = lane >> 4;
  const int wr = wv & 1, wc = wv >> 1;
  const int m0 = blockIdx.x*64, nbase = blockIdx.y*256;
  // stage A: 64 rows x 256 fp32 -> fp16 (16 float4 per thread)
  #pragma unroll
  for (int i = 0; i < 16; ++i){
    int idx = i*256 + t, row = idx >> 6, c4 = idx & 63;
    float4 v = *(const float4*)(X + (size_t)(m0+row)*256 + c4*4);
    h4 o; o[0]=(_Float16)v.x; o[1]=(_Float16)v.y; o[2]=(_Float16)v.z; o[3]=(_Float16)v.w;
    *(h4*)&As[row*264 + c4*4] = o;
  }
  // prefetch first B tile (8 uint4 per thread)
  uint4 bv[8];
  #pragma unroll
  for (int i = 0; i < 8; ++i){
    int idx = i*256 + t, row = idx >> 5, seg = idx & 31;
    bv[i] = *(const uint4*)(Wqkv + (size_t)(nbase+row)*256 + seg*8);
  }
  for (int nt = 0; nt < 4; ++nt){
    const int n0 = nbase + nt*64;
    #pragma unroll
    for (int i = 0; i < 8; ++i){
      int idx = i*256 + t, row = idx >> 5, seg = idx & 31;
      *(uint4*)&Bs[row*264 + seg*8] = bv[i];
    }
    __syncthreads();
    if (nt < 3){
      #pragma unroll
      for (int i = 0; i < 8; ++i){
        int idx = i*256 + t, row = idx >> 5, seg = idx & 31;
        bv[i] = *(const uint4*)(Wqkv + (size_t)(n0 + 64 + row)*256 + seg*8);
      }
    }
    f4 acc[2][2] = {};
    #pragma unroll
    for (int kk = 0; kk < 8; ++kk){
      h8 af[2], bf[2];
      #pragma unroll
      for (int mi = 0; mi < 2; ++mi)
        af[mi] = *(const h8*)&As[(wr*32 + mi*16 + l15)*264 + kk*32 + q*8];
      #pragma unroll
      for (int nj = 0; nj < 2; ++nj)
        bf[nj] = *(const h8*)&Bs[(wc*32 + nj*16 + l15)*264 + kk*32 + q*8];
      #pragma unroll
      for (int mi = 0; mi < 2; ++mi)
      #pragma unroll
      for (int nj = 0; nj < 2; ++nj)
        acc[mi][nj] = __builtin_amdgcn_mfma_f32_16x16x32_f16(af[mi], bf[nj], acc[mi][nj], 0,0,0);
    }
    #pragma unroll
    for (int mi = 0; mi < 2; ++mi)
    #pragma unroll
    for (int nj = 0; nj < 2; ++nj){
      const int og = n0 + wc*32 + nj*16 + l15;
      const int h = og >> 6, j = og & 63;
      const float bs = bias[og];
      #pragma unroll
      for (int r = 0; r < 4; ++r){
        const int mg = m0 + wr*32 + mi*16 + q*4 + r;
        const int b = mg >> 10, n = mg & 1023;
        const size_t bhn = (size_t)(b*8+h)*1024 + n;
        const float v = acc[mi][nj][r] + bs;
        if (j < 16)      Qh[bhn*16 + j]      = (_Float16)(v * QSCALE);
        else if (j < 32) Kh[bhn*16 + (j-16)] = (_Float16)v;
        else             Vh[bhn*32 + (j-32)] = (_Float16)v;
      }
    }
    __syncthreads();
  }
}

// ---------------- proj GEMM: [8192 x 256] x [256 x 256]^T ------------------
__global__ __launch_bounds__(256) void proj_gemm_k(
    const _Float16* __restrict__ A, const _Float16* __restrict__ Wproj,
    const float* __restrict__ bias, float* __restrict__ Out)
{
  __shared__ __align__(16) _Float16 As[64*136];
  __shared__ __align__(16) _Float16 Bs[64*136];
  const int t = threadIdx.x, lane = t & 63, wv = t >> 6;
  const int l15 = lane & 15, q = lane >> 4;
  const int wr = wv & 1, wc = wv >> 1;
  const int m0 = blockIdx.x*64, n0 = blockIdx.y*64;
  uint4 av[4], bv[4];
  #pragma unroll
  for (int i = 0; i < 4; ++i){
    int idx = i*256 + t, row = idx >> 4, seg = idx & 15;
    av[i] = *(const uint4*)(A     + (size_t)(m0+row)*256 + seg*8);
    bv[i] = *(const uint4*)(Wproj + (size_t)(n0+row)*256 + seg*8);
  }
  f4 acc[2][2] = {};
  #pragma unroll
  for (int kc = 0; kc < 2; ++kc){
    #pragma unroll
    for (int i = 0; i < 4; ++i){
      int idx = i*256 + t, row = idx >> 4, seg = idx & 15;
      *(uint4*)&As[row*136 + seg*8] = av[i];
      *(uint4*)&Bs[row*136 + seg*8] = bv[i];
    }
    __syncthreads();
    if (kc == 0){
      #pragma unroll
      for (int i = 0; i < 4; ++i){
        int idx = i*256 + t, row = idx >> 4, seg = idx & 15;
        av[i] = *(const uint4*)(A     + (size_t)(m0+row)*256 + 128 + seg*8);
        bv[i] = *(const uint4*)(Wproj + (size_t)(n0+row)*256 + 128 + seg*8);
      }
    }
    #pragma unroll
    for (int kk = 0; kk < 4; ++kk){
      h8 af[2], bf[2];
      #pragma unroll
      for (int mi = 0; mi < 2; ++mi)
        af[mi] = *(const h8*)&As[(wr*32 + mi*16 + l15)*136 + kk*32 + q*8];
      #pragma unroll
      for (int nj = 0; nj < 2; ++nj)
        bf[nj] = *(const h8*)&Bs[(wc*32 + nj*16 + l15)*136 + kk*32 + q*8];
      #pragma unroll
      for (int mi = 0; mi < 2; ++mi)
      #pragma unroll
      for (int nj = 0; nj < 2; ++nj)
        acc[mi][nj] = __builtin_amdgcn_mfma_f32_16x16x32_f16(af[mi], bf[nj], acc[mi][nj], 0,0,0);
    }
    __syncthreads();
  }
  #pragma unroll
  for (int mi = 0; mi < 2; ++mi)
  #pragma unroll
  for (int nj = 0; nj < 2; ++nj){
    const int og = n0 + wc*32 + nj*16 + l15;
    const float bs = bias[og];
    #pragma unroll
    for (int r = 0; r < 4; ++r){
      const int mg = m0 + wr*32 + mi*16 + q*4 + r;
      Out[(size_t)mg*256 + og] = acc[mi][nj][r] + bs;
    }
  }
}

// ---------------- pass1: rowsum of exp2 over m; Vs[d][n]=V[n][d]/sum -------
// grid (64 bh, 8 nchunk): blockIdx.x = bh -> all blocks of one head land on
// one XCD. K streamed in 128-row chunks (6 KB LDS) with register prefetch.
__global__ __launch_bounds__(256) void pass1_k(
    const _Float16* __restrict__ Qh, const _Float16* __restrict__ Kh,
    const _Float16* __restrict__ Vh, _Float16* __restrict__ Vs)
{
  __shared__ __align__(16) _Float16 Ks[128*24];   // stride 24 halves (48 B)
  const int t = threadIdx.x, lane = t & 63, wv = t >> 6;
  const int l15 = lane & 15, q = lane >> 4;
  const int bh = blockIdx.x;
  const int n0 = blockIdx.y*128 + wv*32;
  const size_t qb = (size_t)bh*1024;
  const h4 af0 = *(const h4*)(Qh + (qb + n0 + l15)*16 + q*4);
  const h4 af1 = *(const h4*)(Qh + (qb + n0 + 16 + l15)*16 + q*4);
  const _Float16* kp = Kh + qb*16;
  const int row = t >> 1, seg = t & 1;
  uint4 kr = *(const uint4*)(kp + row*16 + seg*8);
  f4 sm0 = {0.f,0.f,0.f,0.f}, sm1 = {0.f,0.f,0.f,0.f};
  for (int c = 0; c < 8; ++c){
    *(uint4*)&Ks[row*24 + seg*8] = kr;
    __syncthreads();
    if (c < 7) kr = *(const uint4*)(kp + ((c+1)*128 + row)*16 + seg*8);
    #pragma unroll
    for (int sub = 0; sub < 8; ++sub){
      h4 bf = *(const h4*)&Ks[(sub*16 + l15)*24 + q*4];
      f4 z = {0.f,0.f,0.f,0.f};
      f4 d0 = __builtin_amdgcn_mfma_f32_16x16x16f16(af0, bf, z, 0,0,0);
      f4 d1 = __builtin_amdgcn_mfma_f32_16x16x16f16(af1, bf, z, 0,0,0);
      #pragma unroll
      for (int r = 0; r < 4; ++r){ sm0[r] += ex2(d0[r]); sm1[r] += ex2(d1[r]); }
    }
    __syncthreads();
  }
  #pragma unroll
  for (int st = 1; st < 16; st <<= 1){
    #pragma unroll
    for (int r = 0; r < 4; ++r){
      sm0[r] += __shfl_xor(sm0[r], st, 64);
      sm1[r] += __shfl_xor(sm1[r], st, 64);
    }
  }
  f4 cv0, cv1;
  #pragma unroll
  for (int r = 0; r < 4; ++r){ cv0[r] = 1.0f/sm0[r]; cv1[r] = 1.0f/sm1[r]; }
  #pragma unroll
  for (int half = 0; half < 2; ++half){
    const int dd = l15 + half*16;
    h4 o0, o1;
    #pragma unroll
    for (int r = 0; r < 4; ++r){
      o0[r] = (_Float16)((float)Vh[(qb + n0 + q*4 + r)*32 + dd] * cv0[r]);
      o1[r] = (_Float16)((float)Vh[(qb + n0 + 16 + q*4 + r)*32 + dd] * cv1[r]);
    }
    *(h4*)(Vs + ((size_t)bh*32 + dd)*1024 + n0 + q*4)      = o0;
    *(h4*)(Vs + ((size_t)bh*32 + dd)*1024 + n0 + 16 + q*4) = o1;
  }
}

// ---------------- pass2 + fused pe: X2h = attn_out(view) + dwconv3x3(V) ----
// Main loop identical to R7 (verified). Epilogue: after the Tt transpose,
// each lane's store position (flat f = d*8192 + h*1024 + y*128 + wv*32+mloc)
// equals output coords n_out = d*32 + h*4 + (y>>1), c_out = (y&1)*128 +
// wv*32 + mloc  (algebraic identity with the R7 pe_add mapping). So the
// depthwise 3x3 over V (head h2 = c_out>>5, channel d2 = mloc, spatial
// hs = d, ws = h*4 + (y>>1)) is computed inline and X2h written directly.
__global__ __launch_bounds__(256) void pass2_k(
    const _Float16* __restrict__ Qh, const _Float16* __restrict__ Kh,
    const _Float16* __restrict__ Vs, const _Float16* __restrict__ Vh,
    const float* __restrict__ peW, const float* __restrict__ peB,
    _Float16* __restrict__ X2h)
{
  __shared__ __align__(16) char smem[16896];
  _Float16* Qs  = (_Float16*)smem;                 // [128][24]  6144 B
  _Float16* Vss = (_Float16*)(smem + 6144);        // [32][136]  8704 B
  float*    Tt  = (float*)smem;                    // [4][32*33] 16896 B overlay
  const int t = threadIdx.x, lane = t & 63, wv = t >> 6;
  const int l15 = lane & 15, q = lane >> 4;
  const int bh = blockIdx.x;
  const int b  = bh >> 3, h = bh & 7;
  const int y  = blockIdx.y;
  const int mb = y*128 + wv*32;
  const size_t qb = (size_t)bh*1024;
  const h4 kf0 = *(const h4*)(Kh + (qb + mb + l15)*16 + q*4);
  const h4 kf1 = *(const h4*)(Kh + (qb + mb + 16 + l15)*16 + q*4);
  const _Float16* qp = Qh + qb*16;
  const _Float16* vp = Vs + (size_t)bh*32*1024;
  const int row = t >> 1, seg = t & 1;       // Q staging
  const int vd = t >> 4, vseg = t & 15;      // Vs staging: 2 rounds of 16 d
  uint4 qr = *(const uint4*)(qp + row*16 + seg*8);
  uint4 vr0 = *(const uint4*)(vp + (size_t)vd*1024      + vseg*8);
  uint4 vr1 = *(const uint4*)(vp + (size_t)(vd+16)*1024 + vseg*8);
  f4 a00={0.f,0.f,0.f,0.f}, a01={0.f,0.f,0.f,0.f};
  f4 a10={0.f,0.f,0.f,0.f}, a11={0.f,0.f,0.f,0.f};
  for (int c = 0; c < 8; ++c){
    *(uint4*)&Qs[row*24 + seg*8] = qr;
    *(uint4*)&Vss[vd*136      + vseg*8] = vr0;
    *(uint4*)&Vss[(vd+16)*136 + vseg*8] = vr1;
    __syncthreads();
    if (c < 7){
      const int nn = (c+1)*128;
      qr  = *(const uint4*)(qp + (nn + row)*16 + seg*8);
      vr0 = *(const uint4*)(vp + (size_t)vd*1024      + nn + vseg*8);
      vr1 = *(const uint4*)(vp + (size_t)(vd+16)*1024 + nn + vseg*8);
    }
    #pragma unroll
    for (int sub = 0; sub < 8; ++sub){
      h4 qf = *(const h4*)&Qs[(sub*16 + l15)*24 + q*4];
      h4 b0 = *(const h4*)&Vss[l15*136      + sub*16 + q*4];
      h4 b1 = *(const h4*)&Vss[(16+l15)*136 + sub*16 + q*4];
      f4 z = {0.f,0.f,0.f,0.f};
      f4 s0 = __builtin_amdgcn_mfma_f32_16x16x16f16(qf, kf0, z, 0,0,0);
      f4 s1 = __builtin_amdgcn_mfma_f32_16x16x16f16(qf, kf1, z, 0,0,0);
      h4 p0, p1;
      #pragma unroll
      for (int r = 0; r < 4; ++r){ p0[r] = (_Float16)ex2(s0[r]); p1[r] = (_Float16)ex2(s1[r]); }
      a00 = __builtin_amdgcn_mfma_f32_16x16x16f16(p0, b0, a00, 0,0,0);
      a01 = __builtin_amdgcn_mfma_f32_16x16x16f16(p0, b1, a01, 0,0,0);
      a10 = __builtin_amdgcn_mfma_f32_16x16x16f16(p1, b0, a10, 0,0,0);
      a11 = __builtin_amdgcn_mfma_f32_16x16x16f16(p1, b1, a11, 0,0,0);
    }
    __syncthreads();
  }
  // Transpose 32x32 (m,d) tile through LDS (verified R5/R7 mapping).
  float* tw = Tt + wv*(32*33);
  #pragma unroll
  for (int r = 0; r < 4; ++r){
    tw[(q*4 + r)*33      + l15]      = a00[r];
    tw[(q*4 + r)*33      + 16 + l15] = a01[r];
    tw[(16 + q*4 + r)*33 + l15]      = a10[r];
    tw[(16 + q*4 + r)*33 + 16 + l15] = a11[r];
  }
  __syncthreads();
  // Fused pe epilogue.
  const int mloc = lane & 31, dh = lane >> 5;
  const int wsx = h*4 + (y >> 1);                  // 0..31, block-uniform
  const int c_out = (y & 1)*128 + wv*32 + mloc;    // output channel
  const int h2 = c_out >> 5;                       // wave-uniform head
  const _Float16* vb2 = Vh + (size_t)(b*8 + h2)*32768 + mloc;   // d2 = mloc
  float w9[9];
  #pragma unroll
  for (int kk2 = 0; kk2 < 9; ++kk2) w9[kk2] = peW[kk2*256 + c_out];
  const float pbv = peB[c_out];
  _Float16* xb = X2h + (size_t)b*262144 + (size_t)h*1024 + mb;
  #pragma unroll
  for (int r = 0; r < 16; ++r){
    const int d = r*2 + dh;                        // also hs (spatial row)
    float pe = pbv;
    #pragma unroll
    for (int dy = 0; dy < 3; ++dy){
      const int yy = d + dy - 1;
      if ((unsigned)yy < 32u){
        #pragma unroll
        for (int dx = 0; dx < 3; ++dx){
          const int xx = wsx + dx - 1;
          if ((unsigned)xx < 32u)
            pe += w9[dy*3+dx] * (float)vb2[(size_t)(yy*32 + xx)*32];
        }
      }
    }
    xb[(size_t)d*8192 + mloc] = (_Float16)(tw[mloc*33 + d] + pe);
  }
}

// --------------------------------------------------------------------------
extern "C" void kernel_launch(void* const* d_in, const int* in_sizes, int n_in,
                              void* d_out, int out_size, void* d_ws, size_t ws_size,
                              hipStream_t stream)
{
  const float* X    = (const float*)d_in[0];
  const float* qkvw = (const float*)d_in[1];
  const float* qg   = (const float*)d_in[2];
  const float* qb   = (const float*)d_in[3];
  const float* qm   = (const float*)d_in[4];
  const float* qv   = (const float*)d_in[5];
  const float* pew  = (const float*)d_in[6];
  const float* pg   = (const float*)d_in[7];
  const float* pb   = (const float*)d_in[8];
  const float* pm   = (const float*)d_in[9];
  const float* pv   = (const float*)d_in[10];
  const float* prw  = (const float*)d_in[11];
  const float* prg  = (const float*)d_in[12];
  const float* prb  = (const float*)d_in[13];
  const float* prm  = (const float*)d_in[14];
  const float* prv  = (const float*)d_in[15];

  char* ws = (char*)d_ws;
  _Float16* X2h   = (_Float16*)(ws + 0);          //  4 MB  (b,n,c) flat
  _Float16* Qh    = (_Float16*)(ws + 4194304);    //  2 MB (pre-scaled)
  _Float16* Kh    = (_Float16*)(ws + 6291456);    //  2 MB
  _Float16* Vh    = (_Float16*)(ws + 8388608);    //  4 MB  (bh,n,d)
  _Float16* Vs    = (_Float16*)(ws + 12582912);   //  4 MB  (bh,d,n), /rowsum
  _Float16* Wqkv  = (_Float16*)(ws + 16777216);   //  256 KB [o][c]
  float*    bqkv  = (float*)   (ws + 17039360);   //  2 KB
  _Float16* Wproj = (_Float16*)(ws + 17041408);   //  128 KB [o][c]
  float*    bproj = (float*)   (ws + 17172480);   //  1 KB
  float*    peW   = (float*)   (ws + 17173504);   //  9 KB
  float*    peB   = (float*)   (ws + 17182720);   //  1 KB

  prep_k<<<64, 256, 0, stream>>>(qkvw, qg, qb, qm, qv, pew, pg, pb, pm, pv,
                                 prw, prg, prb, prm, prv,
                                 Wqkv, bqkv, Wproj, bproj, peW, peB);
  qkv_gemm_k<<<dim3(128, 2), 256, 0, stream>>>(X, Wqkv, bqkv, Qh, Kh, Vh);
  pass1_k<<<dim3(64, 8), 256, 0, stream>>>(Qh, Kh, Vh, Vs);
  pass2_k<<<dim3(64, 8), 256, 0, stream>>>(Qh, Kh, Vs, Vh, peW, peB, X2h);
  proj_gemm_k<<<dim3(128, 4), 256, 0, stream>>>(X2h, Wproj, bproj, (float*)d_out);
}